// Round 6
// baseline (34.922 us; speedup 1.0000x reference)
//
#include <hip/hip_runtime.h>

// ResizeFlow: factor-2 trilinear upsample, periodic (dft) wrap, edge anchor,
// then displacement rescale ×2 (folded into z-blend weights: 0.5/1.5).
// Input (2,3,96,96,96) f32 -> Output (2,3,192,192,192) f32.
//
// out[2k]   = 0.25*in[(k-1) mod 96] + 0.75*in[k]
// out[2k+1] = 0.75*in[k]            + 0.25*in[(k+1) mod 96]   (each axis)
//
// R6 single structural change vs R5: brick 4z*4y*4x -> 2z*8y*4x.
// Each wave now touches only 2 output z-planes (was 4) and writes 8
// consecutive y-rows per z (6 KB contiguous span per 48-lane group, was
// 3 KB) -> better DRAM page locality for the 166 MB write stream, which is
// the dominant cost. Reads: 3 planes x 6 rows = 18 row-loads per 64 outputs
// (was 16) -- extra traffic lands in L2 (per-XCD input slab ~2.6 MB).
// Everything else identical: block=64, one-plane-ahead prefetch, chunked
// XCD swizzle, plain float4 stores.

#define ISZ  96
#define OSZ  192
#define NX4  48            // output-x quads per output row
#define NTY  24            // y-bricks (8 output rows each)
#define NTZ  96            // z-bricks (2 output planes each) == input planes
#define ZSTR (ISZ * ISZ)

typedef float vf4 __attribute__((ext_vector_type(4)));

struct Q4 { float a, b, c, d; };          // samples at xa, xm, xm+1, xd
struct PL { Q4 r0, r1, r2, r3, r4, r5; }; // one input plane's 6 rows

__device__ __forceinline__ Q4 q_wsum(float wl, const Q4& L, float wh, const Q4& H) {
    Q4 q;
    q.a = fmaf(wl, L.a, wh * H.a);
    q.b = fmaf(wl, L.b, wh * H.b);
    q.c = fmaf(wl, L.c, wh * H.c);
    q.d = fmaf(wl, L.d, wh * H.d);
    return q;
}
__device__ __forceinline__ Q4 q_scale(float w, const Q4& Y) {
    Q4 q; q.a = w * Y.a; q.b = w * Y.b; q.c = w * Y.c; q.d = w * Y.d; return q;
}
__device__ __forceinline__ void q_acc(Q4& O, float w, const Q4& Y) {
    O.a = fmaf(w, Y.a, O.a);
    O.b = fmaf(w, Y.b, O.b);
    O.c = fmaf(w, Y.c, O.c);
    O.d = fmaf(w, Y.d, O.d);
}

__global__ __launch_bounds__(64)
void resize_flow_kernel(const float* __restrict__ in, float* __restrict__ out) {
    // chunked XCD swizzle (gridDim.x = 10368, divisible by 8)
    unsigned bid = blockIdx.x;
    unsigned wid = (bid & 7u) * (gridDim.x >> 3) + (bid >> 3);
    unsigned t   = wid * 64u + threadIdx.x;

    int x4 = (int)(t % NX4);
    unsigned r = t / NX4;
    int ty = (int)(r % NTY); r /= NTY;
    int k  = (int)(r % NTZ);                // input plane index = z-brick
    int bc = (int)(r / NTZ);                // 0..5

    // input x indices for output quad [4*x4 .. 4*x4+3]
    int xm = 2 * x4;
    int xa = (x4 == 0)       ? ISZ - 1 : xm - 1;
    int xd = (x4 == NX4 - 1) ? 0       : xm + 2;

    // input rows for the 8 output-y rows [8ty .. 8ty+7]: 4ty-1 .. 4ty+4 (wrapped)
    int jy  = 4 * ty;
    int ry0 = (jy == 0) ? ISZ - 1 : jy - 1;
    int ry1 = jy, ry2 = jy + 1, ry3 = jy + 2, ry4 = jy + 3;
    int ry5 = (jy + 4 == ISZ) ? 0 : jy + 4;

    // input planes for output planes {2k, 2k+1}: k-1, k, k+1 (wrapped)
    int km = (k == 0)       ? ISZ - 1 : k - 1;
    int kp = (k == ISZ - 1) ? 0       : k + 1;

    const float* base = in + (size_t)bc * (ISZ * ZSTR);

    auto ld = [&](const float* row) -> Q4 {
        float2 m = *reinterpret_cast<const float2*>(row + xm);  // 8B aligned
        Q4 q; q.a = row[xa]; q.b = m.x; q.c = m.y; q.d = row[xd];
        return q;
    };
    auto load_plane = [&](int p) -> PL {
        const float* pp = base + (size_t)p * ZSTR;
        PL L;
        L.r0 = ld(pp + ry0 * ISZ);
        L.r1 = ld(pp + ry1 * ISZ);
        L.r2 = ld(pp + ry2 * ISZ);
        L.r3 = ld(pp + ry3 * ISZ);
        L.r4 = ld(pp + ry4 * ISZ);
        L.r5 = ld(pp + ry5 * ISZ);
        return L;
    };
    // y-blend one plane's 6 rows into 8 output-y quads (oy = 8ty + i)
    auto yblend = [&](const PL& L, Q4* Y) {
        Y[0] = q_wsum(0.25f, L.r0, 0.75f, L.r1);
        Y[1] = q_wsum(0.75f, L.r1, 0.25f, L.r2);
        Y[2] = q_wsum(0.25f, L.r1, 0.75f, L.r2);
        Y[3] = q_wsum(0.75f, L.r2, 0.25f, L.r3);
        Y[4] = q_wsum(0.25f, L.r2, 0.75f, L.r3);
        Y[5] = q_wsum(0.75f, L.r3, 0.25f, L.r4);
        Y[6] = q_wsum(0.25f, L.r3, 0.75f, L.r4);
        Y[7] = q_wsum(0.75f, L.r4, 0.25f, L.r5);
    };

    int oyb = 8 * ty, ozb = 2 * k;
    auto xstore = [&](const Q4& q, int oz, int dy) {
        vf4 o;
        o.x = fmaf(0.25f, q.a, 0.75f * q.b);
        o.y = fmaf(0.75f, q.b, 0.25f * q.c);
        o.z = fmaf(0.25f, q.b, 0.75f * q.c);
        o.w = fmaf(0.75f, q.c, 0.25f * q.d);
        float* p = out + (((size_t)bc * OSZ + oz) * OSZ + (oyb + dy)) * OSZ + 4 * x4;
        *reinterpret_cast<vf4*>(p) = o;
    };

    // z weights (×2 rescale folded in):
    //   oz = 2k   : 0.5*P(k-1) + 1.5*P(k)
    //   oz = 2k+1 : 1.5*P(k)   + 0.5*P(k+1)
    Q4 Y[8], A[8];

    PL Lm = load_plane(km);
    PL L0 = load_plane(k);                 // prefetch k before blending k-1

    yblend(Lm, Y);
#pragma unroll
    for (int i = 0; i < 8; ++i) A[i] = q_scale(0.5f, Y[i]);

    PL Lp = load_plane(kp);                // prefetch k+1 before blending k

    yblend(L0, Y);
#pragma unroll
    for (int i = 0; i < 8; ++i) q_acc(A[i], 1.5f, Y[i]);
#pragma unroll
    for (int i = 0; i < 8; ++i) xstore(A[i], ozb, i);       // dz = 0
#pragma unroll
    for (int i = 0; i < 8; ++i) A[i] = q_scale(1.5f, Y[i]); // reuse A as B

    yblend(Lp, Y);
#pragma unroll
    for (int i = 0; i < 8; ++i) q_acc(A[i], 0.5f, Y[i]);
#pragma unroll
    for (int i = 0; i < 8; ++i) xstore(A[i], ozb + 1, i);   // dz = 1
}

extern "C" void kernel_launch(void* const* d_in, const int* in_sizes, int n_in,
                              void* d_out, int out_size, void* d_ws, size_t ws_size,
                              hipStream_t stream) {
    const float* in = (const float*)d_in[0];
    float* out = (float*)d_out;

    // 6 * 96 * 24 * 48 = 663,552 threads; 10,368 one-wave blocks (div by 8)
    int total = 6 * NTZ * NTY * NX4;
    int block = 64;
    int grid  = total / block;

    resize_flow_kernel<<<grid, block, 0, stream>>>(in, out);
}